// Round 1
// baseline (393.800 us; speedup 1.0000x reference)
//
#include <hip/hip_runtime.h>
#include <climits>

// Problem constants (from reference): B=4, C=64, H=W=512, NSEG=256.
// Interior crop rows/cols 1..510.
#define NSEG 256
#define CG   8      // channels per block
#define TILES 16    // row-tiles per (batch, channel-group) plane
#define PLANE 262144 // 512*512

// Monotone float->signed-int key: preserves order under signed int compare.
// Involution: applying twice returns original bits.
__device__ __forceinline__ int fkey(float f) {
    int i = __float_as_int(f);
    return i ^ ((i >> 31) & 0x7FFFFFFF);
}

__global__ __launch_bounds__(256) void init_kernel(int* __restrict__ out) {
    out[blockIdx.x * 256 + threadIdx.x] = INT_MIN;
}

__global__ __launch_bounds__(256) void segmax_kernel(const float* __restrict__ feat,
                                                     const int* __restrict__ lab,
                                                     int* __restrict__ out) {
    __shared__ int sm[CG * NSEG];  // 8 KiB of per-label max keys
    const int tid  = threadIdx.x;
    const int tile = blockIdx.x;
    const int cg   = blockIdx.y;
    const int b    = blockIdx.z;
    const int c0   = cg * CG;

    #pragma unroll
    for (int i = tid; i < CG * NSEG; i += 256) sm[i] = INT_MIN;
    __syncthreads();

    // Row range [r_start, r_end) within interior rows 1..510
    const int r_start = 1 + (510 * tile) / TILES;
    const int r_end   = 1 + (510 * (tile + 1)) / TILES;

    const int half   = tid >> 7;          // 0/1: which of 2 rows per iteration
    const int lane_w = (tid & 127) << 2;  // column 0..508, float4 per lane

    const int*   labb = lab  + (size_t)b * PLANE;
    const float* fb   = feat + (size_t)(b * 64 + c0) * PLANE;

    const bool v0 = (lane_w != 0);    // w==0 is border
    const bool v3 = (lane_w != 508);  // w==511 is border

    for (int r = r_start + half; r < r_end; r += 2) {
        const size_t off = (size_t)r * 512 + lane_w;
        const int4 l4 = *(const int4*)(labb + off);
        const int lx = l4.x & 255, ly = l4.y & 255, lz = l4.z & 255, lw = l4.w & 255;
        const float* fp = fb + off;
        #pragma unroll
        for (int c = 0; c < CG; ++c) {
            const float4 f4 = *(const float4*)(fp + (size_t)c * PLANE);
            int* smc = sm + c * NSEG;
            if (v0) atomicMax(smc + lx, fkey(f4.x));
            atomicMax(smc + ly, fkey(f4.y));
            atomicMax(smc + lz, fkey(f4.z));
            if (v3) atomicMax(smc + lw, fkey(f4.w));
        }
    }
    __syncthreads();

    // Merge block-local maxima into global (int-keyed) output.
    int* ob = out + (size_t)(b * 64 + c0) * NSEG;
    #pragma unroll
    for (int i = tid; i < CG * NSEG; i += 256) {
        atomicMax(ob + i, sm[i]);
    }
}

__global__ __launch_bounds__(256) void finalize_kernel(int* __restrict__ out) {
    const int i = blockIdx.x * 256 + threadIdx.x;
    const int k = out[i];
    const float v = (k == INT_MIN) ? 0.0f
                                   : __int_as_float(k ^ ((k >> 31) & 0x7FFFFFFF));
    ((float*)out)[i] = v;
}

extern "C" void kernel_launch(void* const* d_in, const int* in_sizes, int n_in,
                              void* d_out, int out_size, void* d_ws, size_t ws_size,
                              hipStream_t stream) {
    const float* feat = (const float*)d_in[0];   // [4,64,512,512] fp32
    const int*   lab  = (const int*)d_in[1];     // [4,1,512,512] int32
    int* out = (int*)d_out;                      // [4,64,256] fp32 (keyed as int during accum)

    // out_size == 65536
    init_kernel<<<out_size / 256, 256, 0, stream>>>(out);

    dim3 grid(TILES, 64 / CG, 4);
    segmax_kernel<<<grid, 256, 0, stream>>>(feat, lab, out);

    finalize_kernel<<<out_size / 256, 256, 0, stream>>>(out);
}

// Round 2
// 387.443 us; speedup vs baseline: 1.0164x; 1.0164x over previous
//
#include <hip/hip_runtime.h>
#include <climits>

// Problem constants (from reference): B=4, C=64, H=W=512, NSEG=256.
// Interior crop rows/cols 1..510.
#define NSEG 256
#define CG   8       // channels per block
#define TILES 32     // row-tiles per (batch, channel-group) plane -> 4 blocks/CU
#define PLANE 262144 // 512*512

// Monotone float->signed-int key: preserves order under signed int compare.
// Involution: applying twice returns original bits.
__device__ __forceinline__ int fkey(float f) {
    int i = __float_as_int(f);
    return i ^ ((i >> 31) & 0x7FFFFFFF);
}

__global__ __launch_bounds__(256) void init_kernel(int* __restrict__ out) {
    out[blockIdx.x * 256 + threadIdx.x] = INT_MIN;
}

__global__ __launch_bounds__(256) void segmax_kernel(const float* __restrict__ feat,
                                                     const int* __restrict__ lab,
                                                     int* __restrict__ out) {
    __shared__ int sm[CG * NSEG];  // 8 KiB of per-label max keys
    const int tid  = threadIdx.x;
    const int tile = blockIdx.x;
    const int cg   = blockIdx.y;
    const int b    = blockIdx.z;
    const int c0   = cg * CG;

    #pragma unroll
    for (int i = tid; i < CG * NSEG; i += 256) sm[i] = INT_MIN;
    __syncthreads();

    // Row range [r_start, r_end) within interior rows 1..510
    const int r_start = 1 + (510 * tile) / TILES;
    const int r_end   = 1 + (510 * (tile + 1)) / TILES;

    const int half   = tid >> 7;          // 0/1: which of 2 rows per iteration
    const int lane_w = (tid & 127) << 2;  // column 0..508, float4 per lane

    const int*   labb = lab  + (size_t)b * PLANE;
    const float* fb   = feat + (size_t)(b * 64 + c0) * PLANE;

    const bool v0 = (lane_w != 0);    // w==0 is border
    const bool v3 = (lane_w != 508);  // w==511 is border

    for (int r = r_start + half; r < r_end; r += 2) {
        const size_t off = (size_t)r * 512 + lane_w;
        const int4 l4 = *(const int4*)(labb + off);
        const int lx = l4.x & 255, ly = l4.y & 255, lz = l4.z & 255, lw = l4.w & 255;
        const float* fp = fb + off;
        #pragma unroll
        for (int c = 0; c < CG; ++c) {
            const float4 f4 = *(const float4*)(fp + (size_t)c * PLANE);
            int* smc = sm + c * NSEG;
            const int kx = fkey(f4.x), ky = fkey(f4.y), kz = fkey(f4.z), kw = fkey(f4.w);
            // Read-compare guard: plain LDS read (full rate) rejects ~93% of
            // candidates; only new maxima pay the slow ds_max atomic. Stale
            // reads are monotonically smaller -> at worst a redundant atomic.
            if (v0 && kx > smc[lx]) atomicMax(smc + lx, kx);
            if (ky > smc[ly])       atomicMax(smc + ly, ky);
            if (kz > smc[lz])       atomicMax(smc + lz, kz);
            if (v3 && kw > smc[lw]) atomicMax(smc + lw, kw);
        }
    }
    __syncthreads();

    // Merge block-local maxima into global (int-keyed) output, same guard.
    // Global monotone-from-INT_MIN within this kernel => stale reads are only
    // ever smaller => at worst a redundant atomic.
    int* ob = out + (size_t)(b * 64 + c0) * NSEG;
    #pragma unroll
    for (int i = tid; i < CG * NSEG; i += 256) {
        const int v = sm[i];
        if (v > ob[i]) atomicMax(ob + i, v);
    }
}

__global__ __launch_bounds__(256) void finalize_kernel(int* __restrict__ out) {
    const int i = blockIdx.x * 256 + threadIdx.x;
    const int k = out[i];
    const float v = (k == INT_MIN) ? 0.0f
                                   : __int_as_float(k ^ ((k >> 31) & 0x7FFFFFFF));
    ((float*)out)[i] = v;
}

extern "C" void kernel_launch(void* const* d_in, const int* in_sizes, int n_in,
                              void* d_out, int out_size, void* d_ws, size_t ws_size,
                              hipStream_t stream) {
    const float* feat = (const float*)d_in[0];   // [4,64,512,512] fp32
    const int*   lab  = (const int*)d_in[1];     // [4,1,512,512] int32
    int* out = (int*)d_out;                      // [4,64,256] fp32 (keyed as int during accum)

    // out_size == 65536
    init_kernel<<<out_size / 256, 256, 0, stream>>>(out);

    dim3 grid(TILES, 64 / CG, 4);
    segmax_kernel<<<grid, 256, 0, stream>>>(feat, lab, out);

    finalize_kernel<<<out_size / 256, 256, 0, stream>>>(out);
}

// Round 3
// 374.529 us; speedup vs baseline: 1.0515x; 1.0345x over previous
//
#include <hip/hip_runtime.h>
#include <climits>

// Problem constants: B=4, C=64, H=W=512, NSEG=256. Interior rows/cols 1..510.
#define NSEG 256
#define CG   8       // channels per block
#define TILES 64     // row-tiles -> 2048 blocks, ~8/CU
#define PLANE 262144 // 512*512
#define MAXROWS 8    // ceil(510/64)

// Monotone float->signed-int key (involution).
__device__ __forceinline__ int fkey(float f) {
    int i = __float_as_int(f);
    return i ^ ((i >> 31) & 0x7FFFFFFF);
}

__global__ __launch_bounds__(256) void init_kernel(int* __restrict__ out) {
    out[blockIdx.x * 256 + threadIdx.x] = INT_MIN;
}

__global__ __launch_bounds__(256, 4) void segmax_kernel(const float* __restrict__ feat,
                                                        const int* __restrict__ lab,
                                                        int* __restrict__ out) {
    __shared__ int table[CG * NSEG];            // 8 KiB: per-(channel,label) max keys
    __shared__ unsigned labs_w[MAXROWS * 128];  // 4 KiB: byte-packed labels, 4/word

    const int tid  = threadIdx.x;
    const int tile = blockIdx.x;
    const int cg   = blockIdx.y;
    const int b    = blockIdx.z;

    const int r_start = 1 + (510 * tile) / TILES;
    const int r_end   = 1 + (510 * (tile + 1)) / TILES;
    const int nrows   = r_end - r_start;  // 7 or 8

    #pragma unroll
    for (int i = tid; i < CG * NSEG; i += 256) table[i] = INT_MIN;

    // Stage labels for this block's rows into LDS, packed 4 labels/word.
    const int* labb = lab + (size_t)b * PLANE + (size_t)r_start * 512;
    for (int pw = tid; pw < nrows * 128; pw += 256) {
        const int4 l4 = *(const int4*)(labb + pw * 4);
        labs_w[pw] = (unsigned)(l4.x & 255) | ((unsigned)(l4.y & 255) << 8) |
                     ((unsigned)(l4.z & 255) << 16) | ((unsigned)(l4.w & 255) << 24);
    }
    __syncthreads();

    const int half = tid >> 7;           // which of 2 rows per chunk
    const int lw   = tid & 127;          // label word index within row
    const int w    = lw << 2;            // column 0..508
    const bool v0  = (w != 0);           // col 0 is border
    const bool v3  = (w != 508);         // col 511 is border

    // Tail row (chunk 3, half==1) may be out of range for 7-row tiles:
    // clamp the address (always-safe load) and predicate the update.
    const int rl_tail   = (6 + half < nrows) ? (6 + half) : (nrows - 1);
    const bool tail_ok  = (6 + half < nrows);

    const float* fb = feat + (size_t)(b * 64 + cg * CG) * PLANE;

    // Channel-major: one long sequential feature stream per block at a time.
    for (int c = 0; c < CG; ++c) {
        const float* fc = fb + (size_t)c * PLANE + (size_t)r_start * 512;
        int* tc = table + c * NSEG;

        float4 f[4];
        unsigned lu[4];
        #pragma unroll
        for (int k = 0; k < 3; ++k) {  // rows +0..+5: always valid (nrows>=7)
            const int rl = 2 * k + half;
            f[k]  = *(const float4*)(fc + (size_t)rl * 512 + w);
            lu[k] = labs_w[rl * 128 + lw];
        }
        f[3]  = *(const float4*)(fc + (size_t)rl_tail * 512 + w);
        lu[3] = labs_w[rl_tail * 128 + lw];

        #pragma unroll
        for (int k = 0; k < 4; ++k) {
            if (k == 3 && !tail_ok) continue;
            const unsigned u = lu[k];
            const int l0 = u & 255, l1 = (u >> 8) & 255, l2 = (u >> 16) & 255, l3 = u >> 24;
            const int k0 = fkey(f[k].x), k1 = fkey(f[k].y), k2 = fkey(f[k].z), k3 = fkey(f[k].w);
            // Guarded updates: plain LDS read rejects losers; stale reads are
            // monotonically smaller -> at worst a redundant atomic.
            if (v0 && k0 > tc[l0]) atomicMax(tc + l0, k0);
            if (k1 > tc[l1])       atomicMax(tc + l1, k1);
            if (k2 > tc[l2])       atomicMax(tc + l2, k2);
            if (v3 && k3 > tc[l3]) atomicMax(tc + l3, k3);
        }
    }
    __syncthreads();

    // Merge block-local maxima into global (int-keyed) output, guarded.
    int* ob = out + (size_t)(b * 64 + cg * CG) * NSEG;
    #pragma unroll
    for (int i = tid; i < CG * NSEG; i += 256) {
        const int v = table[i];
        if (v > ob[i]) atomicMax(ob + i, v);
    }
}

__global__ __launch_bounds__(256) void finalize_kernel(int* __restrict__ out) {
    const int i = blockIdx.x * 256 + threadIdx.x;
    const int k = out[i];
    const float v = (k == INT_MIN) ? 0.0f
                                   : __int_as_float(k ^ ((k >> 31) & 0x7FFFFFFF));
    ((float*)out)[i] = v;
}

extern "C" void kernel_launch(void* const* d_in, const int* in_sizes, int n_in,
                              void* d_out, int out_size, void* d_ws, size_t ws_size,
                              hipStream_t stream) {
    const float* feat = (const float*)d_in[0];   // [4,64,512,512] fp32
    const int*   lab  = (const int*)d_in[1];     // [4,1,512,512] int32
    int* out = (int*)d_out;                      // [4,64,256] fp32 (int-keyed during accum)

    init_kernel<<<out_size / 256, 256, 0, stream>>>(out);

    dim3 grid(TILES, 64 / CG, 4);
    segmax_kernel<<<grid, 256, 0, stream>>>(feat, lab, out);

    finalize_kernel<<<out_size / 256, 256, 0, stream>>>(out);
}